// Round 3
// baseline (74.517 us; speedup 1.0000x reference)
//
#include <hip/hip_runtime.h>
#include <cstdint>
#include <cstddef>

#define BSZ 16
#define NN  256
#define DE  64
#define DXX 256
#define IB  4        // rows (b,i) per block == waves per block
#define BIGF 100000.0f

// Single fused kernel, barrier-free streaming phase.
// Per block: 4 waves; wave w owns row g0+w entirely (64 KB contiguous).
// Phase A: mask dtype detect (u8/i32/f32) + mask row -> LDS + popcount. (2 barriers)
// Phase B: per-wave one-pass j-reduction, depth-2 pipelined float4 loads,
//          in-wave butterfly, lanes 0-15 write z to LDS. (NO barriers)
// Phase C: one barrier, then z x W^T matvec, thread t = dx.
__global__ __launch_bounds__(256, 4) void etox_fused(
    const float* __restrict__ E, const uint8_t* __restrict__ raw,
    const float* __restrict__ W, const float* __restrict__ bias,
    float* __restrict__ out)
{
    __shared__ float m_lds[NN];
    __shared__ int   det[2];
    __shared__ float cpart[4];
    __shared__ float z_lds[IB][4 * DE];

    const int t    = threadIdx.x;
    const int g0   = blockIdx.x * IB;      // global row = b*NN + i
    const int b    = g0 >> 8;
    const int wv   = t >> 6;
    const int lane = t & 63;

    // ---- phase A: mask dtype detection + mask row ----
    if (t == 0) { det[0] = 0; det[1] = 0; }
    int s1 = 0, s23 = 0;
    {
        const uint8_t* p = raw + t * 16;
        #pragma unroll
        for (int u = 0; u < 16; ++u) {
            int v = (int)p[u];
            int m4 = u & 3;
            if (m4 == 1) s1 += v; else if (m4 >= 2) s23 += v;
        }
    }
    __syncthreads();
    if (s1)  atomicAdd(&det[0], s1);
    if (s23) atomicAdd(&det[1], s23);
    __syncthreads();
    const int kind = (det[1] == 0) ? 1 : ((det[0] == 0) ? 2 : 0);  // 1=i32,2=f32,0=u8

    float mv;
    {
        int idx = b * NN + t;
        if (kind == 1)      mv = (((const int*)(const void*)raw)[idx] != 0) ? 1.f : 0.f;
        else if (kind == 2) mv = (((const float*)(const void*)raw)[idx] != 0.f) ? 1.f : 0.f;
        else                mv = (raw[idx] != 0) ? 1.f : 0.f;
    }
    m_lds[t] = mv;
    unsigned long long bal = __ballot(mv != 0.f);
    if (lane == 0) cpart[wv] = (float)__popcll(bal);
    __syncthreads();
    const float inv_cnt = 1.0f / (cpart[0] + cpart[1] + cpart[2] + cpart[3]);

    // ---- phase B: per-wave barrier-free streaming reduction ----
    const int dq = lane & 15;              // d = 4*dq .. 4*dq+3
    const int jb = lane >> 4;              // j = jb + 4*k, k = 0..63
    const float* rbase = E + (size_t)(g0 + wv) * (NN * DE) + (size_t)jb * DE + 4 * dq;

    #define LD(K) (*(const float4*)(rbase + (size_t)(K) * (4 * DE)))

    float s0=0.f,s1_=0.f,s2=0.f,s3=0.f;
    float ms0=0.f,ms1=0.f,ms2=0.f,ms3=0.f;
    float q0=0.f,q1=0.f,q2=0.f,q3=0.f;
    float mi0=1e30f,mi1=1e30f,mi2=1e30f,mi3=1e30f;
    float ma0=-1e30f,ma1=-1e30f,ma2=-1e30f,ma3=-1e30f;

    #define CONS(V, KK) { \
        float mk = m_lds[jb + 4 * (KK)]; \
        float im = 1.0f - mk; \
        float4 v = V; \
        s0 += v.x; s1_ += v.y; s2 += v.z; s3 += v.w; \
        ms0 = fmaf(mk, v.x, ms0); ms1 = fmaf(mk, v.y, ms1); \
        ms2 = fmaf(mk, v.z, ms2); ms3 = fmaf(mk, v.w, ms3); \
        q0 = fmaf(mk * v.x, v.x, q0); q1 = fmaf(mk * v.y, v.y, q1); \
        q2 = fmaf(mk * v.z, v.z, q2); q3 = fmaf(mk * v.w, v.w, q3); \
        mi0 = fminf(mi0, fmaf(im,  BIGF, v.x)); mi1 = fminf(mi1, fmaf(im,  BIGF, v.y)); \
        mi2 = fminf(mi2, fmaf(im,  BIGF, v.z)); mi3 = fminf(mi3, fmaf(im,  BIGF, v.w)); \
        ma0 = fmaxf(ma0, fmaf(im, -BIGF, v.x)); ma1 = fmaxf(ma1, fmaf(im, -BIGF, v.y)); \
        ma2 = fmaxf(ma2, fmaf(im, -BIGF, v.z)); ma3 = fmaxf(ma3, fmaf(im, -BIGF, v.w)); \
    }

    float4 A0, A1, A2, A3, B0, B1, B2, B3;
    A0 = LD(0); A1 = LD(1); A2 = LD(2); A3 = LD(3);

    #pragma unroll 1
    for (int k = 0; k < 56; k += 8) {
        B0 = LD(k + 4); B1 = LD(k + 5); B2 = LD(k + 6); B3 = LD(k + 7);
        CONS(A0, k + 0) CONS(A1, k + 1) CONS(A2, k + 2) CONS(A3, k + 3)
        A0 = LD(k + 8); A1 = LD(k + 9); A2 = LD(k + 10); A3 = LD(k + 11);
        CONS(B0, k + 4) CONS(B1, k + 5) CONS(B2, k + 6) CONS(B3, k + 7)
    }
    // epilogue k = 56: A holds 56..59, load 60..63, no further prefetch
    B0 = LD(60); B1 = LD(61); B2 = LD(62); B3 = LD(63);
    CONS(A0, 56) CONS(A1, 57) CONS(A2, 58) CONS(A3, 59)
    CONS(B0, 60) CONS(B1, 61) CONS(B2, 62) CONS(B3, 63)
    #undef CONS
    #undef LD

    // in-wave butterfly across jb (lane bits 4,5)
    #define RED_ADD(x) { x += __shfl_xor(x, 16); x += __shfl_xor(x, 32); }
    #define RED_MIN(x) { x = fminf(x, __shfl_xor(x, 16)); x = fminf(x, __shfl_xor(x, 32)); }
    #define RED_MAX(x) { x = fmaxf(x, __shfl_xor(x, 16)); x = fmaxf(x, __shfl_xor(x, 32)); }
    RED_ADD(s0) RED_ADD(s1_) RED_ADD(s2) RED_ADD(s3)
    RED_ADD(ms0) RED_ADD(ms1) RED_ADD(ms2) RED_ADD(ms3)
    RED_ADD(q0) RED_ADD(q1) RED_ADD(q2) RED_ADD(q3)
    RED_MIN(mi0) RED_MIN(mi1) RED_MIN(mi2) RED_MIN(mi3)
    RED_MAX(ma0) RED_MAX(ma1) RED_MAX(ma2) RED_MAX(ma3)
    #undef RED_ADD
    #undef RED_MIN
    #undef RED_MAX

    // lanes 0-15 now hold full-row stats for d = 4*dq..4*dq+3
    {
        float m0 = s0 * inv_cnt, m1 = s1_ * inv_cnt, m2 = s2 * inv_cnt, m3 = s3 * inv_cnt;
        float sd0 = q0 * inv_cnt - 2.f * m0 * (ms0 * inv_cnt) + m0 * m0;
        float sd1 = q1 * inv_cnt - 2.f * m1 * (ms1 * inv_cnt) + m1 * m1;
        float sd2 = q2 * inv_cnt - 2.f * m2 * (ms2 * inv_cnt) + m2 * m2;
        float sd3 = q3 * inv_cnt - 2.f * m3 * (ms3 * inv_cnt) + m3 * m3;
        if (lane < 16) {
            float* zr = z_lds[wv];
            *(float4*)(zr + 4 * dq)       = make_float4(m0, m1, m2, m3);
            *(float4*)(zr + 64 + 4 * dq)  = make_float4(mi0, mi1, mi2, mi3);
            *(float4*)(zr + 128 + 4 * dq) = make_float4(ma0, ma1, ma2, ma3);
            *(float4*)(zr + 192 + 4 * dq) = make_float4(sd0, sd1, sd2, sd3);
        }
    }
    __syncthreads();   // z complete

    // ---- phase C: matvec, thread t = dx ----
    float acc0, acc1, acc2, acc3;
    {
        float bv = bias[t];
        acc0 = bv; acc1 = bv; acc2 = bv; acc3 = bv;
    }
    const float4* Wrow = (const float4*)(W + (size_t)t * 4 * DE);
    #pragma unroll 8
    for (int f4 = 0; f4 < 64; ++f4) {
        float4 w4 = Wrow[f4];
        int f = 4 * f4;
        acc0 += z_lds[0][f] * w4.x + z_lds[0][f+1] * w4.y + z_lds[0][f+2] * w4.z + z_lds[0][f+3] * w4.w;
        acc1 += z_lds[1][f] * w4.x + z_lds[1][f+1] * w4.y + z_lds[1][f+2] * w4.z + z_lds[1][f+3] * w4.w;
        acc2 += z_lds[2][f] * w4.x + z_lds[2][f+1] * w4.y + z_lds[2][f+2] * w4.z + z_lds[2][f+3] * w4.w;
        acc3 += z_lds[3][f] * w4.x + z_lds[3][f+1] * w4.y + z_lds[3][f+2] * w4.z + z_lds[3][f+3] * w4.w;
    }
    out[(size_t)(g0 + 0) * DXX + t] = acc0;
    out[(size_t)(g0 + 1) * DXX + t] = acc1;
    out[(size_t)(g0 + 2) * DXX + t] = acc2;
    out[(size_t)(g0 + 3) * DXX + t] = acc3;
}

extern "C" void kernel_launch(void* const* d_in, const int* in_sizes, int n_in,
                              void* d_out, int out_size, void* d_ws, size_t ws_size,
                              hipStream_t stream) {
    const float*   E    = (const float*)d_in[0];
    const uint8_t* mraw = (const uint8_t*)d_in[1];
    const float*   W    = (const float*)d_in[2];
    const float*   bias = (const float*)d_in[3];
    float*         out  = (float*)d_out;

    etox_fused<<<(BSZ * NN) / IB, 256, 0, stream>>>(E, mraw, W, bias, out);
}

// Round 5
// 74.273 us; speedup vs baseline: 1.0033x; 1.0033x over previous
//
#include <hip/hip_runtime.h>
#include <cstdint>
#include <cstddef>

#define BSZ 16
#define NN  256
#define DE  64
#define DXX 256
#define IB  4   // rows (b,i) per block

typedef float nfloat4 __attribute__((ext_vector_type(4)));

// R2 structure (best so far). Single change: E loads are NON-TEMPORAL
// (nt bit -> no L2/L3 install) so the 268 MB once-per-pass stream runs on
// the HBM path instead of the hypothesized ~3.8 TB/s L3-hit path.
__global__ __launch_bounds__(256, 4) void etox_fused(
    const float* __restrict__ E, const uint8_t* __restrict__ raw,
    const float* __restrict__ W, const float* __restrict__ bias,
    float* __restrict__ out)
{
    __shared__ float m_lds[NN];
    __shared__ int   det[2];
    __shared__ float cpart[4];
    __shared__ float partial[4][16][20];   // [wave][dquad][acc]
    __shared__ float z_lds[IB][4 * DE];

    const int t   = threadIdx.x;
    const int g0  = blockIdx.x * IB;       // global row = b*NN + i
    const int b   = g0 >> 8;

    // ---- phase A: mask dtype detection + mask row ----
    if (t == 0) { det[0] = 0; det[1] = 0; }
    int s1 = 0, s23 = 0;
    {
        const uint8_t* p = raw + t * 16;
        #pragma unroll
        for (int u = 0; u < 16; ++u) {
            int v = (int)p[u];
            int m4 = u & 3;
            if (m4 == 1) s1 += v; else if (m4 >= 2) s23 += v;
        }
    }
    __syncthreads();
    if (s1)  atomicAdd(&det[0], s1);
    if (s23) atomicAdd(&det[1], s23);
    __syncthreads();
    const int kind = (det[1] == 0) ? 1 : ((det[0] == 0) ? 2 : 0);  // 1=i32,2=f32,0=u8

    float mv;
    {
        int idx = b * NN + t;
        if (kind == 1)      mv = (((const int*)(const void*)raw)[idx] != 0) ? 1.f : 0.f;
        else if (kind == 2) mv = (((const float*)(const void*)raw)[idx] != 0.f) ? 1.f : 0.f;
        else                mv = (raw[idx] != 0) ? 1.f : 0.f;
    }
    m_lds[t] = mv;
    unsigned long long bal = __ballot(mv != 0.f);
    const int wv = t >> 6, lane = t & 63;
    if (lane == 0) cpart[wv] = (float)__popcll(bal);
    __syncthreads();
    const float inv_cnt = 1.0f / (cpart[0] + cpart[1] + cpart[2] + cpart[3]);

    // ---- phase B: pipelined one-pass reductions (nt loads) ----
    const int dq = t & 15;                 // d = 4*dq .. 4*dq+3
    const int jb = t >> 4;                 // j = jb + 16*k, k = 0..15
    const float* base0 = E + (size_t)g0 * (NN * DE) + (size_t)jb * DE + 4 * dq;

    #define LD(P, K) (__builtin_nontemporal_load((const nfloat4*)((P) + (size_t)(K) * (16 * DE))))
    nfloat4 A0, A1, A2, A3, B0, B1, B2, B3;
    A0 = LD(base0, 0); A1 = LD(base0, 1); A2 = LD(base0, 2); A3 = LD(base0, 3);

    for (int r = 0; r < IB; ++r) {
        const float* baser = base0 + (size_t)r * (NN * DE);

        float s[4]  = {0.f, 0.f, 0.f, 0.f};
        float ms[4] = {0.f, 0.f, 0.f, 0.f};
        float q[4]  = {0.f, 0.f, 0.f, 0.f};
        float mi[4] = {1e30f, 1e30f, 1e30f, 1e30f};
        float ma[4] = {-1e30f, -1e30f, -1e30f, -1e30f};

        #define CONS1(V, KK) { \
            float mk = m_lds[jb + 16 * (KK)]; \
            bool on = (mk != 0.f); \
            nfloat4 v = V; \
            s[0] += v.x; s[1] += v.y; s[2] += v.z; s[3] += v.w; \
            ms[0] = fmaf(mk, v.x, ms[0]); ms[1] = fmaf(mk, v.y, ms[1]); \
            ms[2] = fmaf(mk, v.z, ms[2]); ms[3] = fmaf(mk, v.w, ms[3]); \
            q[0] = fmaf(mk * v.x, v.x, q[0]); q[1] = fmaf(mk * v.y, v.y, q[1]); \
            q[2] = fmaf(mk * v.z, v.z, q[2]); q[3] = fmaf(mk * v.w, v.w, q[3]); \
            mi[0] = fminf(mi[0], on ? v.x : 1e30f); mi[1] = fminf(mi[1], on ? v.y : 1e30f); \
            mi[2] = fminf(mi[2], on ? v.z : 1e30f); mi[3] = fminf(mi[3], on ? v.w : 1e30f); \
            ma[0] = fmaxf(ma[0], on ? v.x : -1e30f); ma[1] = fmaxf(ma[1], on ? v.y : -1e30f); \
            ma[2] = fmaxf(ma[2], on ? v.z : -1e30f); ma[3] = fmaxf(ma[3], on ? v.w : -1e30f); \
        }

        B0 = LD(baser, 4);  B1 = LD(baser, 5);  B2 = LD(baser, 6);  B3 = LD(baser, 7);
        CONS1(A0, 0) CONS1(A1, 1) CONS1(A2, 2) CONS1(A3, 3)
        A0 = LD(baser, 8);  A1 = LD(baser, 9);  A2 = LD(baser, 10); A3 = LD(baser, 11);
        CONS1(B0, 4) CONS1(B1, 5) CONS1(B2, 6) CONS1(B3, 7)
        B0 = LD(baser, 12); B1 = LD(baser, 13); B2 = LD(baser, 14); B3 = LD(baser, 15);
        CONS1(A0, 8) CONS1(A1, 9) CONS1(A2, 10) CONS1(A3, 11)
        if (r < IB - 1) {   // prefetch next row's batch 0 across the barriers
            const float* basen = baser + (NN * DE);
            A0 = LD(basen, 0); A1 = LD(basen, 1); A2 = LD(basen, 2); A3 = LD(basen, 3);
        }
        CONS1(B0, 12) CONS1(B1, 13) CONS1(B2, 14) CONS1(B3, 15)
        #undef CONS1

        // butterfly reduce across the 4 j-groups within this wave
        #pragma unroll
        for (int c = 0; c < 4; ++c) {
            s[c]  += __shfl_xor(s[c], 16);  s[c]  += __shfl_xor(s[c], 32);
            ms[c] += __shfl_xor(ms[c], 16); ms[c] += __shfl_xor(ms[c], 32);
            q[c]  += __shfl_xor(q[c], 16);  q[c]  += __shfl_xor(q[c], 32);
            mi[c] = fminf(mi[c], __shfl_xor(mi[c], 16));
            mi[c] = fminf(mi[c], __shfl_xor(mi[c], 32));
            ma[c] = fmaxf(ma[c], __shfl_xor(ma[c], 16));
            ma[c] = fmaxf(ma[c], __shfl_xor(ma[c], 32));
        }

        if (lane < 16) {
            float* p = partial[wv][lane];
            #pragma unroll
            for (int c = 0; c < 4; ++c) {
                p[c]      = s[c];
                p[4 + c]  = ms[c];
                p[8 + c]  = q[c];
                p[12 + c] = mi[c];
                p[16 + c] = ma[c];
            }
        }
        __syncthreads();

        if (t < 64) {
            const int d = t, dq2 = d >> 2, c = d & 3;
            float ss = 0.f, mss = 0.f, mq = 0.f, lmi = 1e30f, lma = -1e30f;
            #pragma unroll
            for (int w = 0; w < 4; ++w) {
                const float* p = partial[w][dq2];
                ss  += p[c];
                mss += p[4 + c];
                mq  += p[8 + c];
                lmi  = fminf(lmi, p[12 + c]);
                lma  = fmaxf(lma, p[16 + c]);
            }
            float m    = ss * inv_cnt;
            float stdv = mq * inv_cnt - 2.0f * m * (mss * inv_cnt) + m * m;
            z_lds[r][d]       = m;
            z_lds[r][64 + d]  = lmi;
            z_lds[r][128 + d] = lma;
            z_lds[r][192 + d] = stdv;
        }
        __syncthreads();   // partial[] reuse next row / z_lds complete
    }
    #undef LD

    // ---- phase C: matvec, thread t = dx ----
    float acc0, acc1, acc2, acc3;
    {
        float bv = bias[t];
        acc0 = bv; acc1 = bv; acc2 = bv; acc3 = bv;
    }
    const float4* Wrow = (const float4*)(W + (size_t)t * 4 * DE);
    #pragma unroll 8
    for (int f4 = 0; f4 < 64; ++f4) {
        float4 w4 = Wrow[f4];
        int f = 4 * f4;
        acc0 += z_lds[0][f] * w4.x + z_lds[0][f+1] * w4.y + z_lds[0][f+2] * w4.z + z_lds[0][f+3] * w4.w;
        acc1 += z_lds[1][f] * w4.x + z_lds[1][f+1] * w4.y + z_lds[1][f+2] * w4.z + z_lds[1][f+3] * w4.w;
        acc2 += z_lds[2][f] * w4.x + z_lds[2][f+1] * w4.y + z_lds[2][f+2] * w4.z + z_lds[2][f+3] * w4.w;
        acc3 += z_lds[3][f] * w4.x + z_lds[3][f+1] * w4.y + z_lds[3][f+2] * w4.z + z_lds[3][f+3] * w4.w;
    }
    out[(size_t)(g0 + 0) * DXX + t] = acc0;
    out[(size_t)(g0 + 1) * DXX + t] = acc1;
    out[(size_t)(g0 + 2) * DXX + t] = acc2;
    out[(size_t)(g0 + 3) * DXX + t] = acc3;
}

extern "C" void kernel_launch(void* const* d_in, const int* in_sizes, int n_in,
                              void* d_out, int out_size, void* d_ws, size_t ws_size,
                              hipStream_t stream) {
    const float*   E    = (const float*)d_in[0];
    const uint8_t* mraw = (const uint8_t*)d_in[1];
    const float*   W    = (const float*)d_in[2];
    const float*   bias = (const float*)d_in[3];
    float*         out  = (float*)d_out;

    etox_fused<<<(BSZ * NN) / IB, 256, 0, stream>>>(E, mraw, W, bias, out);
}